// Round 7
// baseline (196.301 us; speedup 1.0000x reference)
//
#include <hip/hip_runtime.h>
#include <hip/hip_bf16.h>
#include <string.h>

// Problem constants
#define NB    4096      // batch rows
#define IND_  512       // feature dim
#define OUTD_ 512       // output dim (GEMM M, "o")
#define XCOLS 514       // P + IND
#define ND    25        // D^P
#define KTOT  12800     // IND_*ND
#define NSPL  4         // split over 4 i-windows

// Wt (fragment-order W) geometry: Wt[d][og][iw][lane][32]
//   d in [0,25), og in [0,32) (16-row o-groups), iw in [0,4), lane in [0,64)
//   d-stride = 32*4*2048 = 262144; bias block at WT_BIAS + og*2048
#define WT_DS   262144
#define WT_BIAS 6553600   // 25*262144; +32*2048 = 6,619,136 total (= old size)

// GEMM tiling (v9: 64x128 block, 4 waves x (16o x 128b), ALL-REGISTER,
//              coalesced fragment-order A loads, 3 waves/SIMD)
#define BM 64
#define BN 128

// prep_w tiling (R18-proven v2 load stage)
#define PWI 64
#define PWO 4
#define PWC (PWO * ND)   // 100 columns (o_l*25 + d)
#define T8P 112          // tile8 padded byte stride

typedef float  f32x4  __attribute__((ext_vector_type(4)));
typedef int    i32x4  __attribute__((ext_vector_type(4)));
typedef int    i32x8  __attribute__((ext_vector_type(8)));
typedef unsigned short u16x4 __attribute__((ext_vector_type(4)));
typedef unsigned int   u32x2 __attribute__((ext_vector_type(2)));

__device__ __forceinline__ unsigned short f2bf(float f) {
  unsigned int x = __float_as_uint(f);
  return (unsigned short)((x + 0x7fffu + ((x >> 16) & 1u)) >> 16);
}

__device__ __forceinline__ float bf2f(unsigned short u) {
  return __uint_as_float(((unsigned int)u) << 16);
}

__device__ __forceinline__ unsigned int pk_bf16(float a, float b) {
  return (unsigned int)f2bf(a) | ((unsigned int)f2bf(b) << 16);
}

// Software fp32 -> OCP e4m3fn, RNE, for v >= 0 (all values < 1.2).
__device__ __forceinline__ unsigned char f2fp8(float v) {
  if (v < 0.015625f) {
    return (unsigned char)__float2int_rn(v * 512.0f);
  }
  unsigned int u = __float_as_uint(v);
  u += 0x7ffffu + ((u >> 20) & 1u);
  int e = (int)(u >> 23) - 127 + 7;
  unsigned int m = (u >> 20) & 7u;
  return (unsigned char)((e << 3) | m);
}

__device__ __forceinline__ float basis_f(float t, int j) {
  switch (j) {
    case 0: return 1.0f;
    case 1: return t;
    case 2: return t * t;
    case 3: { float r = t - 0.33f; r = r > 0.0f ? r : 0.0f; return r * r; }
    default:{ float r = t - 0.66f; r = r > 0.0f ? r : 0.0f; return r * r; }
  }
}

// ---------------------------------------------------------------------------
// prep_all v4: load stages unchanged (R18-proven); STORE layouts changed to
// feed gemm v9:
//   - W -> Wt in exact MFMA A-fragment order (coalesced gemm loads)
//   - kbDT -> [d][bt][l15][nf] so gemm reads dk as 2 x dwordx4 per iter
//   - bias -> Wt bias block (fragment order, K-window 3)
// ---------------------------------------------------------------------------
__global__ __launch_bounds__(256) void prep_all_kernel(
    const float* __restrict__ x, const float* __restrict__ W,
    const float* __restrict__ bias, unsigned char* __restrict__ Xf8,
    float* __restrict__ kbDT, unsigned char* __restrict__ kbT8,
    unsigned char* __restrict__ Wt, float* __restrict__ out)
{
  __shared__ unsigned char tile8[PWI * T8P];   // 7 KB
  const int bid = blockIdx.x;
  const int tid = threadIdx.x;

  if (bid < 512) {
    const int lane = tid & 63;
    #pragma unroll
    for (int rr = 0; rr < 2; ++rr) {
      const int b = bid * 8 + (tid >> 6) * 2 + rr;
      const float* xr = x + (size_t)b * XCOLS;
      const float* fp = xr + 2 + lane * 8;
      float2 a0 = *(const float2*)(fp + 0);
      float2 a1 = *(const float2*)(fp + 2);
      float2 a2 = *(const float2*)(fp + 4);
      float2 a3 = *(const float2*)(fp + 6);
      float xf[8] = {a0.x, a0.y, a1.x, a1.y, a2.x, a2.y, a3.x, a3.y};
      u32x2 pk;
      pk[0] = (unsigned int)f2fp8(xf[0]) | ((unsigned int)f2fp8(xf[1]) << 8) |
              ((unsigned int)f2fp8(xf[2]) << 16) | ((unsigned int)f2fp8(xf[3]) << 24);
      pk[1] = (unsigned int)f2fp8(xf[4]) | ((unsigned int)f2fp8(xf[5]) << 8) |
              ((unsigned int)f2fp8(xf[6]) << 16) | ((unsigned int)f2fp8(xf[7]) << 24);
      *reinterpret_cast<u32x2*>(Xf8 + (size_t)b * IND_ + lane * 8) = pk;

      float t0 = xr[0], t1 = xr[1];
      if (lane < 2) out[(size_t)b * XCOLS + lane] = (lane == 0) ? t0 : t1;
      {
        // telescoping difference dk_d = kv_d - kv_{d+1} (kv_25 := 0),
        // stored as kbDT[((d*32 + bt)*16 + (b&15))*8 + ((b>>4)&7)]
        int d1 = lane / 5, d2 = lane - d1 * 5;
        float kvd = basis_f(t0, d1) * basis_f(t1, d2);
        float kvn = 0.0f;
        if (lane < 24) {
          int e1 = (lane + 1) / 5, e2 = (lane + 1) - e1 * 5;
          kvn = basis_f(t0, e1) * basis_f(t1, e2);
        }
        if (lane < ND) {
          int bt = b >> 7, bl = b & 15, nf = (b >> 4) & 7;
          kbDT[(((size_t)lane * 32 + bt) * 16 + bl) * 8 + nf] = kvd - kvn;
        }
      }
      {
        int ta = 2 * lane, tb = 2 * lane + 1;
        unsigned char ba = 0, bb = 0;
        if (ta < ND) { int d1 = ta / 5, d2 = ta - d1 * 5;
                       ba = f2fp8(basis_f(t0, d1) * basis_f(t1, d2)); }
        if (tb < ND) { int d1 = tb / 5, d2 = tb - d1 * 5;
                       bb = f2fp8(basis_f(t0, d1) * basis_f(t1, d2)); }
        *(unsigned short*)(kbT8 + (size_t)b * 128 + 2 * lane) =
            (unsigned short)ba | ((unsigned short)bb << 8);
      }
    }
  } else {
    const int pw = bid - 512;
    const int i0 = (pw & 7) * PWI;
    const int o0 = (pw >> 3) * PWO;

    for (int t = tid; t < PWI * (PWC / 4); t += 256) {
      int il = t / (PWC / 4);
      int c4 = t - il * (PWC / 4);
      float4 v = *(const float4*)(W + ((size_t)(i0 + il) * OUTD_ + o0) * ND + c4 * 4);
      unsigned int pk = (unsigned int)f2fp8(v.x) | ((unsigned int)f2fp8(v.y) << 8) |
                        ((unsigned int)f2fp8(v.z) << 16) | ((unsigned int)f2fp8(v.w) << 24);
      *(unsigned int*)&tile8[il * T8P + c4 * 4] = pk;
    }
    __syncthreads();

    // byte-gather into FRAGMENT-ORDER Wt:
    //   dest(d, o, ib) = (((d*32 + o>>4)*4 + ib>>7)*2048
    //                    + ((ib&127)>>5)*512 + (o&15)*32 + (ib&31)
    for (int g = tid; g < PWC * (PWI / 8); g += 256) {
      int c  = g >> 3;
      int ig = g & 7;
      int d  = c % 25;
      int o_l = c / 25;
      unsigned long long v = 0;
      #pragma unroll
      for (int jj = 0; jj < 8; ++jj)
        v |= (unsigned long long)tile8[(ig * 8 + jj) * T8P + c] << (8 * jj);
      int o  = o0 + o_l;
      int ib = i0 + ig * 8;            // [0,512)
      int iw = ib >> 7;
      int wb = ib & 127;
      size_t dest = (((size_t)d * 32 + (o >> 4)) * 4 + iw) * 2048
                  + (size_t)(((wb >> 5) * 16 + (o & 15)) * 32 + (wb & 31));
      *reinterpret_cast<unsigned long long*>(Wt + dest) = v;
    }

    if ((pw & 7) == 0) {
      // bias block: fragment order at WT_BIAS + og*2048
      int o = o0 + (tid >> 6);
      int p = tid & 63;
      int ta = 2 * p, tb = 2 * p + 1;
      unsigned char ba = (ta < ND) ? f2fp8(bias[o * ND + ta]) : (unsigned char)0;
      unsigned char bb = (tb < ND) ? f2fp8(bias[o * ND + tb]) : (unsigned char)0;
      size_t dest = WT_BIAS + (size_t)(o >> 4) * 2048
                  + (size_t)(((ta >> 5) * 16 + (o & 15)) * 32 + (ta & 31));
      *(unsigned short*)(Wt + dest) =
          (unsigned short)ba | ((unsigned short)bb << 8);
    }
  }
}

// ---------------------------------------------------------------------------
// gemm_mx v9: ALL-REGISTER (R4-R6-proven dataflow), latency-hardened.
//
// R24 post-mortem of v8: spill gone (WRITE 16.4 MB = Pb), MFMA busy 10.2 us
// = the floor, but 46 us of stall: 2 waves/SIMD (regs 192), A-loads a
// 16-line gather (lane addr = row*12928 + quad*32), prefetch ~1 thin iter.
// Latency-bound on all three axes.
//
// v9 fixes:
//  (1) Wt fragment-order layout -> per-iter A load = 2 coalesced
//      global_load_dwordx4 over a contiguous wave-span (zero divergence).
//  (2) wave = 16o x 128b: one A-frag/wave/iter, no cross-wave A dup,
//      regs ~160 total (bfr 64 + acc 32 + fin 32 + abuf 16 + dk/addr ~16)
//      -> 3 waves/SIMD, enforced by __launch_bounds__(256,3) (cap 170).
//  (3) dk as 2 x dwordx4 per iter (kbDT fragment layout).
// No LDS / barriers / DMA / asm.  Telescoping dk flush (R21-proven).
// Grid 1024 = 8(o) x 4(iw) x 32(b); id&7 = o-tile (XCD-pinned A panel).
// ---------------------------------------------------------------------------
__global__ __launch_bounds__(256, 3) void gemm_mx_kernel(
    const unsigned char* __restrict__ Wt, const unsigned char* __restrict__ Xf8,
    const float* __restrict__ kbDT, const unsigned char* __restrict__ kbT8,
    unsigned short* __restrict__ Pb)
{
  const int tid  = threadIdx.x;
  const int lane = tid & 63;
  const int w    = tid >> 6;            // [0,4)
  const int l15  = lane & 15;
  const int quad = lane >> 4;

  const int id = blockIdx.x;            // [0,1024)
  const int ox = id & 7;                // o-tile of 64 [0,8)  (XCD-pinned)
  const int iw = (id >> 3) & 3;         // i-window (split) [0,4)
  const int by = id >> 5;               // b-tile [0,32)

  const int o0 = ox * BM;
  const int b0 = by * BN;
  const bool tail = (iw == 3);
  const int og = ox * 4 + w;            // global 16-row o-group [0,32)

  // helper: load a 32-B fragment into i32x8
  auto load8 = [](const unsigned char* p) -> i32x8 {
    i32x4 lo = *reinterpret_cast<const i32x4*>(p);
    i32x4 hi = *reinterpret_cast<const i32x4*>(p + 16);
    i32x8 v;
    v[0] = lo[0]; v[1] = lo[1]; v[2] = lo[2]; v[3] = lo[3];
    v[4] = hi[0]; v[5] = hi[1]; v[6] = hi[2]; v[7] = hi[3];
    return v;
  };

  // ---- B fragments once (held for the whole kernel): 64 regs ----
  i32x8 bfr[8];
  #pragma unroll
  for (int nf = 0; nf < 8; ++nf)
    bfr[nf] = load8(Xf8 + (size_t)(b0 + nf * 16 + l15) * IND_ + iw * 128 + quad * 32);

  // ---- A pointer: fragment-order, contiguous per wave; +WT_DS per iter ----
  const unsigned char* aP =
      Wt + ((size_t)og * 4 + iw) * 2048 + lane * 32;

  // ---- dk pointer: kbDT[((d*32+by)*16+l15)*8]; +4096 floats per d ----
  const float* dP = kbDT + (((size_t)by * 16 + l15) * 8);

  f32x4 acc[8], fin[8];
  #pragma unroll
  for (int nf = 0; nf < 8; ++nf) { acc[nf] = (f32x4)0.0f; fin[nf] = (f32x4)0.0f; }

  // 8 MFMAs (telescoping: acc never reset) + dk-scaled flush into fin
  auto mfma_flush = [&](const i32x8& a, const f32x4& q0, const f32x4& q1) {
    #pragma unroll
    for (int nf = 0; nf < 8; ++nf)
      acc[nf] = __builtin_amdgcn_mfma_scale_f32_16x16x128_f8f6f4(
          a, bfr[nf], acc[nf], 0, 0, 0, 0x7f7f7f7f, 0, 0x7f7f7f7f);
    #pragma unroll
    for (int nf = 0; nf < 4; ++nf)
      #pragma unroll
      for (int r = 0; r < 4; ++r)
        fin[nf][r] += q0[nf] * acc[nf][r];
    #pragma unroll
    for (int nf = 4; nf < 8; ++nf)
      #pragma unroll
      for (int r = 0; r < 4; ++r)
        fin[nf][r] += q1[nf - 4] * acc[nf][r];
  };

  // ---- prologue: A(0) ----
  i32x8 a0 = load8(aP), a1;

  // ---- main loop: 24 iters in 12 unrolled-2 passes, static double-buffer.
  for (int pass = 0; pass < 12; ++pass) {
    a1 = load8(aP + WT_DS);                            // A(n+1)
    f32x4 q0 = *reinterpret_cast<const f32x4*>(dP);
    f32x4 q1 = *reinterpret_cast<const f32x4*>(dP + 4);
    mfma_flush(a0, q0, q1);

    a0 = load8(aP + 2 * WT_DS);                        // A(n+2)
    q0 = *reinterpret_cast<const f32x4*>(dP + 4096);
    q1 = *reinterpret_cast<const f32x4*>(dP + 4100);
    mfma_flush(a1, q0, q1);

    aP += 2 * WT_DS;
    dP += 8192;
  }

  // ---- peeled iter 24 (a0 holds A(24)); bias-A prefetch for iw==3 ----
  if (tail) a1 = load8(Wt + WT_BIAS + (size_t)og * 2048 + lane * 32);
  {
    f32x4 q0 = *reinterpret_cast<const f32x4*>(dP);
    f32x4 q1 = *reinterpret_cast<const f32x4*>(dP + 4);
    mfma_flush(a0, q0, q1);
  }

  // ---- bias K-tail (iw==3): B = kbT8 fragments, accumulate into fin ----
  if (tail) {
    i32x8 bft[8];
    #pragma unroll
    for (int nf = 0; nf < 8; ++nf)
      bft[nf] = load8(kbT8 + (size_t)(b0 + nf * 16 + l15) * 128 + quad * 32);
    #pragma unroll
    for (int nf = 0; nf < 8; ++nf)
      fin[nf] = __builtin_amdgcn_mfma_scale_f32_16x16x128_f8f6f4(
          a1, bft[nf], fin[nf], 0, 0, 0, 0x7f7f7f7f, 0, 0x7f7f7f7f);
  }

  // ---- store partial as bf16 ----
  unsigned short* Pz = Pb + (size_t)iw * NB * OUTD_;
  #pragma unroll
  for (int nf = 0; nf < 8; ++nf) {
    int bg = b0 + nf * 16 + l15;
    int oo = o0 + w * 16 + quad * 4;
    u32x2 pk;
    pk[0] = pk_bf16(fin[nf][0], fin[nf][1]);
    pk[1] = pk_bf16(fin[nf][2], fin[nf][3]);
    *reinterpret_cast<u32x2*>(&Pz[(size_t)bg * OUTD_ + oo]) = pk;
  }
}

// ---------------------------------------------------------------------------
// epilogue: out[b][2+o..2+o+3] = relu(P0+P1+P2+P3)  (bias in K-tail)
// ---------------------------------------------------------------------------
__global__ __launch_bounds__(256) void epilogue_kernel(
    const unsigned short* __restrict__ Pb, float* __restrict__ out)
{
  const int idx = (blockIdx.x * 256 + threadIdx.x) * 4;   // < 4096*512
  const int b = idx >> 9;
  const int o = idx & 511;
  const size_t ps = (size_t)NB * OUTD_;
  float s[4] = {0.0f, 0.0f, 0.0f, 0.0f};
  #pragma unroll
  for (int z = 0; z < NSPL; ++z) {
    u16x4 v = *reinterpret_cast<const u16x4*>(&Pb[z * ps + idx]);
    #pragma unroll
    for (int e = 0; e < 4; ++e) s[e] += bf2f(v[e]);
  }
  float* op = out + (size_t)b * XCOLS + 2 + o;   // 8B-aligned
  float2 lo, hi;
  lo.x = s[0] > 0.0f ? s[0] : 0.0f;
  lo.y = s[1] > 0.0f ? s[1] : 0.0f;
  hi.x = s[2] > 0.0f ? s[2] : 0.0f;
  hi.y = s[3] > 0.0f ? s[3] : 0.0f;
  *(float2*)op = lo;
  *(float2*)(op + 2) = hi;
}

// ---------------------------------------------------------------------------
extern "C" void kernel_launch(void* const* d_in, const int* in_sizes, int n_in,
                              void* d_out, int out_size, void* d_ws, size_t ws_size,
                              hipStream_t stream) {
  const float* x    = (const float*)d_in[0];   // 4096 x 514
  const float* W    = (const float*)d_in[1];   // 512 x 512 x 25
  const float* bias = (const float*)d_in[2];   // 512 x 25
  float* out = (float*)d_out;
  char* ws = (char*)d_ws;

  // ws layout (bytes):
  //   Xf8 2,097,152 | Wt 6,619,136 | kbDT 25*4096*4 = 409,600
  //   kbT8 524,288 | Pb 4*4096*512*2 = 16,777,216   (total ~26.4 MB)
  const size_t xf_off  = 0;
  const size_t wf_off  = 2097152;
  const size_t kb_off  = wf_off + 6619136;
  const size_t kbt_off = kb_off + 409600;
  const size_t p_off   = kbt_off + (size_t)NB * 128;
  unsigned char* Xf8  = (unsigned char*)(ws + xf_off);
  unsigned char* Wt   = (unsigned char*)(ws + wf_off);
  float* kbDT         = (float*)(ws + kb_off);
  unsigned char* kbT8 = (unsigned char*)(ws + kbt_off);
  unsigned short* Pb  = (unsigned short*)(ws + p_off);

  prep_all_kernel<<<1536, 256, 0, stream>>>(x, W, bias, Xf8, kbDT, kbT8, Wt, out);
  gemm_mx_kernel<<<1024, 256, 0, stream>>>(Wt, Xf8, kbDT, kbT8, Pb);
  epilogue_kernel<<<(NB * OUTD_) / 1024, 256, 0, stream>>>(Pb, out);
}

// Round 8
// 128.042 us; speedup vs baseline: 1.5331x; 1.5331x over previous
//
#include <hip/hip_runtime.h>
#include <hip/hip_bf16.h>
#include <string.h>

// Problem constants
#define NB    4096      // batch rows
#define IND_  512       // feature dim
#define OUTD_ 512       // output dim (GEMM M, "o")
#define XCOLS 514       // P + IND
#define ND    25        // D^P
#define KTOT  12800     // IND_*ND
#define NSPL  4         // split over 4 i-windows

// Wt (fragment-order W) geometry: Wt[d][og][iw][lane][32]
//   d in [0,25), og in [0,32) (16-row o-groups), iw in [0,4), lane in [0,64)
//   d-stride = 32*4*2048 = 262144; bias block at WT_BIAS + og*2048
#define WT_DS   262144
#define WT_BIAS 6553600   // 25*262144; +32*2048 = 6,619,136 total

// GEMM tiling (v10: 64x128 block, 4 waves x (16o x 128b), ALL-REGISTER,
//              coalesced fragment-order A loads, depth-3 prefetch,
//              SPILL-FREE budget: __launch_bounds__(256,2))
#define BM 64
#define BN 128

// prep_w tiling (R18-proven v2 load stage)
#define PWI 64
#define PWO 4
#define PWC (PWO * ND)   // 100 columns (o_l*25 + d)
#define T8P 112          // tile8 padded byte stride

typedef float  f32x4  __attribute__((ext_vector_type(4)));
typedef int    i32x4  __attribute__((ext_vector_type(4)));
typedef int    i32x8  __attribute__((ext_vector_type(8)));
typedef unsigned short u16x4 __attribute__((ext_vector_type(4)));
typedef unsigned int   u32x2 __attribute__((ext_vector_type(2)));

__device__ __forceinline__ unsigned short f2bf(float f) {
  unsigned int x = __float_as_uint(f);
  return (unsigned short)((x + 0x7fffu + ((x >> 16) & 1u)) >> 16);
}

__device__ __forceinline__ float bf2f(unsigned short u) {
  return __uint_as_float(((unsigned int)u) << 16);
}

__device__ __forceinline__ unsigned int pk_bf16(float a, float b) {
  return (unsigned int)f2bf(a) | ((unsigned int)f2bf(b) << 16);
}

// Software fp32 -> OCP e4m3fn, RNE, for v >= 0 (all values < 1.2).
__device__ __forceinline__ unsigned char f2fp8(float v) {
  if (v < 0.015625f) {
    return (unsigned char)__float2int_rn(v * 512.0f);
  }
  unsigned int u = __float_as_uint(v);
  u += 0x7ffffu + ((u >> 20) & 1u);
  int e = (int)(u >> 23) - 127 + 7;
  unsigned int m = (u >> 20) & 7u;
  return (unsigned char)((e << 3) | m);
}

__device__ __forceinline__ float basis_f(float t, int j) {
  switch (j) {
    case 0: return 1.0f;
    case 1: return t;
    case 2: return t * t;
    case 3: { float r = t - 0.33f; r = r > 0.0f ? r : 0.0f; return r * r; }
    default:{ float r = t - 0.66f; r = r > 0.0f ? r : 0.0f; return r * r; }
  }
}

// ---------------------------------------------------------------------------
// prep_all v4 (R7-proven, unchanged): fragment-order Wt, fragment-order
// kbDT [d][bt][l15][nf], bias block in Wt.
// ---------------------------------------------------------------------------
__global__ __launch_bounds__(256) void prep_all_kernel(
    const float* __restrict__ x, const float* __restrict__ W,
    const float* __restrict__ bias, unsigned char* __restrict__ Xf8,
    float* __restrict__ kbDT, unsigned char* __restrict__ kbT8,
    unsigned char* __restrict__ Wt, float* __restrict__ out)
{
  __shared__ unsigned char tile8[PWI * T8P];   // 7 KB
  const int bid = blockIdx.x;
  const int tid = threadIdx.x;

  if (bid < 512) {
    const int lane = tid & 63;
    #pragma unroll
    for (int rr = 0; rr < 2; ++rr) {
      const int b = bid * 8 + (tid >> 6) * 2 + rr;
      const float* xr = x + (size_t)b * XCOLS;
      const float* fp = xr + 2 + lane * 8;
      float2 a0 = *(const float2*)(fp + 0);
      float2 a1 = *(const float2*)(fp + 2);
      float2 a2 = *(const float2*)(fp + 4);
      float2 a3 = *(const float2*)(fp + 6);
      float xf[8] = {a0.x, a0.y, a1.x, a1.y, a2.x, a2.y, a3.x, a3.y};
      u32x2 pk;
      pk[0] = (unsigned int)f2fp8(xf[0]) | ((unsigned int)f2fp8(xf[1]) << 8) |
              ((unsigned int)f2fp8(xf[2]) << 16) | ((unsigned int)f2fp8(xf[3]) << 24);
      pk[1] = (unsigned int)f2fp8(xf[4]) | ((unsigned int)f2fp8(xf[5]) << 8) |
              ((unsigned int)f2fp8(xf[6]) << 16) | ((unsigned int)f2fp8(xf[7]) << 24);
      *reinterpret_cast<u32x2*>(Xf8 + (size_t)b * IND_ + lane * 8) = pk;

      float t0 = xr[0], t1 = xr[1];
      if (lane < 2) out[(size_t)b * XCOLS + lane] = (lane == 0) ? t0 : t1;
      {
        // telescoping difference dk_d = kv_d - kv_{d+1} (kv_25 := 0),
        // stored as kbDT[((d*32 + bt)*16 + (b&15))*8 + ((b>>4)&7)]
        int d1 = lane / 5, d2 = lane - d1 * 5;
        float kvd = basis_f(t0, d1) * basis_f(t1, d2);
        float kvn = 0.0f;
        if (lane < 24) {
          int e1 = (lane + 1) / 5, e2 = (lane + 1) - e1 * 5;
          kvn = basis_f(t0, e1) * basis_f(t1, e2);
        }
        if (lane < ND) {
          int bt = b >> 7, bl = b & 15, nf = (b >> 4) & 7;
          kbDT[(((size_t)lane * 32 + bt) * 16 + bl) * 8 + nf] = kvd - kvn;
        }
      }
      {
        int ta = 2 * lane, tb = 2 * lane + 1;
        unsigned char ba = 0, bb = 0;
        if (ta < ND) { int d1 = ta / 5, d2 = ta - d1 * 5;
                       ba = f2fp8(basis_f(t0, d1) * basis_f(t1, d2)); }
        if (tb < ND) { int d1 = tb / 5, d2 = tb - d1 * 5;
                       bb = f2fp8(basis_f(t0, d1) * basis_f(t1, d2)); }
        *(unsigned short*)(kbT8 + (size_t)b * 128 + 2 * lane) =
            (unsigned short)ba | ((unsigned short)bb << 8);
      }
    }
  } else {
    const int pw = bid - 512;
    const int i0 = (pw & 7) * PWI;
    const int o0 = (pw >> 3) * PWO;

    for (int t = tid; t < PWI * (PWC / 4); t += 256) {
      int il = t / (PWC / 4);
      int c4 = t - il * (PWC / 4);
      float4 v = *(const float4*)(W + ((size_t)(i0 + il) * OUTD_ + o0) * ND + c4 * 4);
      unsigned int pk = (unsigned int)f2fp8(v.x) | ((unsigned int)f2fp8(v.y) << 8) |
                        ((unsigned int)f2fp8(v.z) << 16) | ((unsigned int)f2fp8(v.w) << 24);
      *(unsigned int*)&tile8[il * T8P + c4 * 4] = pk;
    }
    __syncthreads();

    // byte-gather into FRAGMENT-ORDER Wt:
    //   dest(d, o, ib) = (((d*32 + o>>4)*4 + ib>>7)*2048
    //                    + ((ib&127)>>5)*512 + (o&15)*32 + (ib&31)
    for (int g = tid; g < PWC * (PWI / 8); g += 256) {
      int c  = g >> 3;
      int ig = g & 7;
      int d  = c % 25;
      int o_l = c / 25;
      unsigned long long v = 0;
      #pragma unroll
      for (int jj = 0; jj < 8; ++jj)
        v |= (unsigned long long)tile8[(ig * 8 + jj) * T8P + c] << (8 * jj);
      int o  = o0 + o_l;
      int ib = i0 + ig * 8;            // [0,512)
      int iw = ib >> 7;
      int wb = ib & 127;
      size_t dest = (((size_t)d * 32 + (o >> 4)) * 4 + iw) * 2048
                  + (size_t)(((wb >> 5) * 16 + (o & 15)) * 32 + (wb & 31));
      *reinterpret_cast<unsigned long long*>(Wt + dest) = v;
    }

    if ((pw & 7) == 0) {
      // bias block: fragment order at WT_BIAS + og*2048
      int o = o0 + (tid >> 6);
      int p = tid & 63;
      int ta = 2 * p, tb = 2 * p + 1;
      unsigned char ba = (ta < ND) ? f2fp8(bias[o * ND + ta]) : (unsigned char)0;
      unsigned char bb = (tb < ND) ? f2fp8(bias[o * ND + tb]) : (unsigned char)0;
      size_t dest = WT_BIAS + (size_t)(o >> 4) * 2048
                  + (size_t)(((ta >> 5) * 16 + (o & 15)) * 32 + (ta & 31));
      *(unsigned short*)(Wt + dest) =
          (unsigned short)ba | ((unsigned short)bb << 8);
    }
  }
}

// ---------------------------------------------------------------------------
// gemm_mx v10: v9's coalesced fragment-order dataflow, SPILL-FREE budget.
//
// R25 post-mortem of v9: the (256,3) bound (cap 512/3 ~= 170 regs) sat
// below the ~185-reg demand -> allocator spilled ~20 regs in-loop ->
// WRITE 89.8 MB scratch, gemm 119 us.  Ledger R4-R7: this dataflow spills
// at cap <=170, is clean at cap 256 (R6: WRITE == Pb exactly).
//
// v10: __launch_bounds__(256,2) (cap 256, proven clean regime; 2 waves/
// SIMD) and DEPTH-3 A prefetch (a0/a1/a2 rotation, 8 passes x 3 iters):
// prefetch lead = 2 full iters ~= 1104 SIMD-cyc > 900-cyc HBM-miss
// latency.  Latency is covered by depth instead of occupancy.
// The final pass prefetches A(25) which overruns Wt by ~196 KB into the
// kbDT region — in-workspace, never consumed (the bias tail reloads a1
// from the bias block).  Everything else identical to v9: coalesced
// per-iter A load (2 x dwordx4 over a contiguous 2 KB wave-span),
// dk as 2 x dwordx4, telescoping flush, no LDS/barriers/DMA/asm.
// Grid 1024 = 8(o) x 4(iw) x 32(b); id&7 = o-tile (XCD-pinned A panel).
// ---------------------------------------------------------------------------
__global__ __launch_bounds__(256, 2) void gemm_mx_kernel(
    const unsigned char* __restrict__ Wt, const unsigned char* __restrict__ Xf8,
    const float* __restrict__ kbDT, const unsigned char* __restrict__ kbT8,
    unsigned short* __restrict__ Pb)
{
  const int tid  = threadIdx.x;
  const int lane = tid & 63;
  const int w    = tid >> 6;            // [0,4)
  const int l15  = lane & 15;
  const int quad = lane >> 4;

  const int id = blockIdx.x;            // [0,1024)
  const int ox = id & 7;                // o-tile of 64 [0,8)  (XCD-pinned)
  const int iw = (id >> 3) & 3;         // i-window (split) [0,4)
  const int by = id >> 5;               // b-tile [0,32)

  const int o0 = ox * BM;
  const int b0 = by * BN;
  const bool tail = (iw == 3);
  const int og = ox * 4 + w;            // global 16-row o-group [0,32)

  // helper: load a 32-B fragment into i32x8
  auto load8 = [](const unsigned char* p) -> i32x8 {
    i32x4 lo = *reinterpret_cast<const i32x4*>(p);
    i32x4 hi = *reinterpret_cast<const i32x4*>(p + 16);
    i32x8 v;
    v[0] = lo[0]; v[1] = lo[1]; v[2] = lo[2]; v[3] = lo[3];
    v[4] = hi[0]; v[5] = hi[1]; v[6] = hi[2]; v[7] = hi[3];
    return v;
  };

  // ---- B fragments once (held for the whole kernel): 64 regs ----
  i32x8 bfr[8];
  #pragma unroll
  for (int nf = 0; nf < 8; ++nf)
    bfr[nf] = load8(Xf8 + (size_t)(b0 + nf * 16 + l15) * IND_ + iw * 128 + quad * 32);

  // ---- A pointer: fragment-order, contiguous per wave; +WT_DS per iter ----
  const unsigned char* aP =
      Wt + ((size_t)og * 4 + iw) * 2048 + lane * 32;

  // ---- dk pointer: kbDT[((d*32+by)*16+l15)*8]; +4096 floats per d ----
  const float* dP = kbDT + (((size_t)by * 16 + l15) * 8);

  f32x4 acc[8], fin[8];
  #pragma unroll
  for (int nf = 0; nf < 8; ++nf) { acc[nf] = (f32x4)0.0f; fin[nf] = (f32x4)0.0f; }

  // 8 MFMAs (telescoping: acc never reset) + dk-scaled flush into fin
  auto mfma_flush = [&](const i32x8& a, const f32x4& q0, const f32x4& q1) {
    #pragma unroll
    for (int nf = 0; nf < 8; ++nf)
      acc[nf] = __builtin_amdgcn_mfma_scale_f32_16x16x128_f8f6f4(
          a, bfr[nf], acc[nf], 0, 0, 0, 0x7f7f7f7f, 0, 0x7f7f7f7f);
    #pragma unroll
    for (int nf = 0; nf < 4; ++nf)
      #pragma unroll
      for (int r = 0; r < 4; ++r)
        fin[nf][r] += q0[nf] * acc[nf][r];
    #pragma unroll
    for (int nf = 4; nf < 8; ++nf)
      #pragma unroll
      for (int r = 0; r < 4; ++r)
        fin[nf][r] += q1[nf - 4] * acc[nf][r];
  };

  // ---- prologue: A(0), A(1) in flight ----
  i32x8 a0 = load8(aP);
  i32x8 a1 = load8(aP + WT_DS);
  i32x8 a2;

  // ---- main loop: 24 iters in 8 unrolled-3 passes, static triple-buffer.
  // Pass invariant: a0 = A(n), a1 = A(n+1) in flight; dP at d = n.
  for (int pass = 0; pass < 8; ++pass) {
    a2 = load8(aP + 2 * WT_DS);                        // A(n+2)
    f32x4 q0 = *reinterpret_cast<const f32x4*>(dP);
    f32x4 q1 = *reinterpret_cast<const f32x4*>(dP + 4);
    mfma_flush(a0, q0, q1);

    a0 = load8(aP + 3 * WT_DS);                        // A(n+3)
    q0 = *reinterpret_cast<const f32x4*>(dP + 4096);
    q1 = *reinterpret_cast<const f32x4*>(dP + 4100);
    mfma_flush(a1, q0, q1);

    a1 = load8(aP + 4 * WT_DS);                        // A(n+4); last pass
    q0 = *reinterpret_cast<const f32x4*>(dP + 8192);   //   reads past Wt —
    q1 = *reinterpret_cast<const f32x4*>(dP + 8196);   //   in-ws, unused
    mfma_flush(a2, q0, q1);

    aP += 3 * WT_DS;
    dP += 12288;
  }

  // ---- peeled iter 24 (a0 = A(24)); bias-A reload for iw==3 ----
  if (tail) a1 = load8(Wt + WT_BIAS + (size_t)og * 2048 + lane * 32);
  {
    f32x4 q0 = *reinterpret_cast<const f32x4*>(dP);
    f32x4 q1 = *reinterpret_cast<const f32x4*>(dP + 4);
    mfma_flush(a0, q0, q1);
  }

  // ---- bias K-tail (iw==3): B = kbT8 fragments, accumulate into fin ----
  if (tail) {
    i32x8 bft[8];
    #pragma unroll
    for (int nf = 0; nf < 8; ++nf)
      bft[nf] = load8(kbT8 + (size_t)(b0 + nf * 16 + l15) * 128 + quad * 32);
    #pragma unroll
    for (int nf = 0; nf < 8; ++nf)
      fin[nf] = __builtin_amdgcn_mfma_scale_f32_16x16x128_f8f6f4(
          a1, bft[nf], fin[nf], 0, 0, 0, 0x7f7f7f7f, 0, 0x7f7f7f7f);
  }

  // ---- store partial as bf16 ----
  unsigned short* Pz = Pb + (size_t)iw * NB * OUTD_;
  #pragma unroll
  for (int nf = 0; nf < 8; ++nf) {
    int bg = b0 + nf * 16 + l15;
    int oo = o0 + w * 16 + quad * 4;
    u32x2 pk;
    pk[0] = pk_bf16(fin[nf][0], fin[nf][1]);
    pk[1] = pk_bf16(fin[nf][2], fin[nf][3]);
    *reinterpret_cast<u32x2*>(&Pz[(size_t)bg * OUTD_ + oo]) = pk;
  }
}

// ---------------------------------------------------------------------------
// epilogue: out[b][2+o..2+o+3] = relu(P0+P1+P2+P3)  (bias in K-tail)
// ---------------------------------------------------------------------------
__global__ __launch_bounds__(256) void epilogue_kernel(
    const unsigned short* __restrict__ Pb, float* __restrict__ out)
{
  const int idx = (blockIdx.x * 256 + threadIdx.x) * 4;   // < 4096*512
  const int b = idx >> 9;
  const int o = idx & 511;
  const size_t ps = (size_t)NB * OUTD_;
  float s[4] = {0.0f, 0.0f, 0.0f, 0.0f};
  #pragma unroll
  for (int z = 0; z < NSPL; ++z) {
    u16x4 v = *reinterpret_cast<const u16x4*>(&Pb[z * ps + idx]);
    #pragma unroll
    for (int e = 0; e < 4; ++e) s[e] += bf2f(v[e]);
  }
  float* op = out + (size_t)b * XCOLS + 2 + o;   // 8B-aligned
  float2 lo, hi;
  lo.x = s[0] > 0.0f ? s[0] : 0.0f;
  lo.y = s[1] > 0.0f ? s[1] : 0.0f;
  hi.x = s[2] > 0.0f ? s[2] : 0.0f;
  hi.y = s[3] > 0.0f ? s[3] : 0.0f;
  *(float2*)op = lo;
  *(float2*)(op + 2) = hi;
}

// ---------------------------------------------------------------------------
extern "C" void kernel_launch(void* const* d_in, const int* in_sizes, int n_in,
                              void* d_out, int out_size, void* d_ws, size_t ws_size,
                              hipStream_t stream) {
  const float* x    = (const float*)d_in[0];   // 4096 x 514
  const float* W    = (const float*)d_in[1];   // 512 x 512 x 25
  const float* bias = (const float*)d_in[2];   // 512 x 25
  float* out = (float*)d_out;
  char* ws = (char*)d_ws;

  // ws layout (bytes):
  //   Xf8 2,097,152 | Wt 6,619,136 | kbDT 25*4096*4 = 409,600
  //   kbT8 524,288 | Pb 4*4096*512*2 = 16,777,216   (total ~26.4 MB)
  const size_t xf_off  = 0;
  const size_t wf_off  = 2097152;
  const size_t kb_off  = wf_off + 6619136;
  const size_t kbt_off = kb_off + 409600;
  const size_t p_off   = kbt_off + (size_t)NB * 128;
  unsigned char* Xf8  = (unsigned char*)(ws + xf_off);
  unsigned char* Wt   = (unsigned char*)(ws + wf_off);
  float* kbDT         = (float*)(ws + kb_off);
  unsigned char* kbT8 = (unsigned char*)(ws + kbt_off);
  unsigned short* Pb  = (unsigned short*)(ws + p_off);

  prep_all_kernel<<<1536, 256, 0, stream>>>(x, W, bias, Xf8, kbDT, kbT8, Wt, out);
  gemm_mx_kernel<<<1024, 256, 0, stream>>>(Wt, Xf8, kbDT, kbT8, Pb);
  epilogue_kernel<<<(NB * OUTD_) / 1024, 256, 0, stream>>>(Pb, out);
}